// Round 16
// baseline (553.903 us; speedup 1.0000x reference)
//
#include <hip/hip_runtime.h>
#include <hip/hip_bf16.h>

// ---------- helpers ----------

__device__ __forceinline__ unsigned short f2bf(float f) {
    unsigned u = __float_as_uint(f);
    unsigned r = u + 0x7fffu + ((u >> 16) & 1u);
    return (unsigned short)(r >> 16);
}

typedef __bf16 bf16_t;
typedef bf16_t bf16x8 __attribute__((ext_vector_type(8)));
typedef float f32x4 __attribute__((ext_vector_type(4)));

typedef const __attribute__((address_space(1))) unsigned int* gptr_t;
typedef __attribute__((address_space(3))) unsigned int* lptr_t;

__device__ __forceinline__ void gload_lds16(const void* g, void* l) {
    __builtin_amdgcn_global_load_lds((gptr_t)g, (lptr_t)l, 16, 0, 0);
}

// ---------- kernel 1: fused column-max of |x| AND column-max+convert of W ----------
__global__ void maxes_kernel(const float* __restrict__ x, int xrows,
                             const float* __restrict__ W, int wrows,
                             unsigned int* __restrict__ ma, unsigned int* __restrict__ mw,
                             unsigned short* __restrict__ Wb, int cols, int xBlocks) {
    int c = (blockIdx.x * blockDim.x + threadIdx.x) * 4;
    if (c >= cols) return;
    float m0 = 0.f, m1 = 0.f, m2 = 0.f, m3 = 0.f;
    if ((int)blockIdx.y < xBlocks) {
        int r0 = blockIdx.y * 64;
        int r1 = min(r0 + 64, xrows);
        const float* p = x + (size_t)r0 * cols + c;
        for (int r = r0; r < r1; ++r, p += cols) {
            float4 v = *(const float4*)p;
            m0 = fmaxf(m0, fabsf(v.x));
            m1 = fmaxf(m1, fabsf(v.y));
            m2 = fmaxf(m2, fabsf(v.z));
            m3 = fmaxf(m3, fabsf(v.w));
        }
        atomicMax(ma + c + 0, __float_as_uint(m0));
        atomicMax(ma + c + 1, __float_as_uint(m1));
        atomicMax(ma + c + 2, __float_as_uint(m2));
        atomicMax(ma + c + 3, __float_as_uint(m3));
    } else {
        int r0 = ((int)blockIdx.y - xBlocks) * 64;
        int r1 = min(r0 + 64, wrows);
        const float* p = W + (size_t)r0 * cols + c;
        unsigned short* q = Wb + (size_t)r0 * cols + c;
        for (int r = r0; r < r1; ++r, p += cols, q += cols) {
            float4 v = *(const float4*)p;
            ushort4 o;
            o.x = f2bf(v.x); o.y = f2bf(v.y); o.z = f2bf(v.z); o.w = f2bf(v.w);
            *(ushort4*)q = o;
            m0 = fmaxf(m0, fabsf(v.x));
            m1 = fmaxf(m1, fabsf(v.y));
            m2 = fmaxf(m2, fabsf(v.z));
            m3 = fmaxf(m3, fabsf(v.w));
        }
        atomicMax(mw + c + 0, __float_as_uint(m0));
        atomicMax(mw + c + 1, __float_as_uint(m1));
        atomicMax(mw + c + 2, __float_as_uint(m2));
        atomicMax(mw + c + 3, __float_as_uint(m3));
    }
}

// ---------- kernel 2: 2:4 prune of (x/s), s computed inline ----------
__global__ void prune_kernel(const float* __restrict__ x,
                             const unsigned int* __restrict__ ma,
                             const unsigned int* __restrict__ mw,
                             unsigned short* __restrict__ xsp, size_t ngroups, int cols) {
    size_t g = (size_t)blockIdx.x * blockDim.x + threadIdx.x;
    size_t stride = (size_t)gridDim.x * blockDim.x;
    for (; g < ngroups; g += stride) {
        size_t e = g * 4;
        int cb = (int)(e & (size_t)(cols - 1));
        float4 v = *(const float4*)(x + e);
        uint4 mav = *(const uint4*)(ma + cb);
        uint4 mwv = *(const uint4*)(mw + cb);
        float s0 = sqrtf(__uint_as_float(mav.x) / fmaxf(__uint_as_float(mwv.x), 1e-8f));
        float s1 = sqrtf(__uint_as_float(mav.y) / fmaxf(__uint_as_float(mwv.y), 1e-8f));
        float s2 = sqrtf(__uint_as_float(mav.z) / fmaxf(__uint_as_float(mwv.z), 1e-8f));
        float s3 = sqrtf(__uint_as_float(mav.w) / fmaxf(__uint_as_float(mwv.w), 1e-8f));
        float a0 = fabsf(v.x / s0);
        float a1 = fabsf(v.y / s1);
        float a2 = fabsf(v.z / s2);
        float a3 = fabsf(v.w / s3);
        int r0 = 0, r1 = 0, r2 = 0, r3 = 0;
        if (a1 > a0) r0++; else r1++;
        if (a2 > a0) r0++; else r2++;
        if (a3 > a0) r0++; else r3++;
        if (a2 > a1) r1++; else r2++;
        if (a3 > a1) r1++; else r3++;
        if (a3 > a2) r2++; else r3++;
        ushort4 o;
        o.x = (r0 < 2) ? f2bf(v.x) : (unsigned short)0;
        o.y = (r1 < 2) ? f2bf(v.y) : (unsigned short)0;
        o.z = (r2 < 2) ? f2bf(v.z) : (unsigned short)0;
        o.w = (r3 < 2) ? f2bf(v.w) : (unsigned short)0;
        *(ushort4*)(xsp + e) = o;
    }
}

// ---------- kernel 3: 256x256 bf16 B^T GEMM, quadrant phases + early reads ----------
// 4 phases/K-tile, 16 MFMA each (quads (0,0),(0,1),(1,1),(1,0)). Each phase's
// MFMA consumes frags ds_read-ISSUED >=1 phase earlier; the compiler emits
// minimal COUNTED lgkm waits (no manual lgkmcnt(0) -> reads hide under MFMA).
// Read issue: bv1@q1, af1@q2, af0'(t+1)@q3, bv0'(t+1)@q4 — peak frag liveness
// ~96-116 VGPR, fits the ~128 VGPR budget (acc is in AGPRs).
// Stage 1 half-tile/phase into buf[(t+1)&1]: A0@q1, B0@q2, B1@q3, A1@q4.
// Uniform counted vmcnt(2)/phase; FIFO (verified): q1 drains A1(t) [read q2],
// q2 drains A0(t+1) [read q3], q3 drains B0(t+1) [read q4], q4 drains B1(t+1)
// [read q1(t+1)] — every drain 1 barrier before first read; 1 half-tile always
// in flight. Every stage targets a region whose reads drained >=4 barriers ago.

template <int ISB, int H>
__device__ __forceinline__ void stage_half(const unsigned short* __restrict__ G, int ldk,
                                           long blockBase, int k0, unsigned short* sbuf,
                                           int wid, int l) {
#pragma unroll
    for (int j = 0; j < 2; ++j) {
        int rho0;
        if (ISB) rho0 = ((wid * 8) & 31) + (wid >> 2) * 64 + H * 32 + j * 128;
        else     rho0 = wid * 8 + H * 64 + j * 128;
        int rho = rho0 + (l >> 3);
        int c = l & 7;
        const unsigned short* src =
            G + (size_t)(blockBase + rho) * ldk + k0 + ((c ^ (rho & 7)) << 3);
        gload_lds16(src, (char*)sbuf + rho0 * 128);
    }
}

#define STAGE_A0(k, buf) stage_half<0, 0>(A, K, browBase, (k), (buf), wid, l)
#define STAGE_A1(k, buf) stage_half<0, 1>(A, K, browBase, (k), (buf), wid, l)
#define STAGE_B0(k, buf) stage_half<1, 0>(B, K, bcolBase, (k), (buf), wid, l)
#define STAGE_B1(k, buf) stage_half<1, 1>(B, K, bcolBase, (k), (buf), wid, l)

#define LOAD_AF(dst, MH, srcbuf)                                                    \
    _Pragma("unroll") for (int mm = 0; mm < 4; ++mm)                                \
        _Pragma("unroll") for (int kk = 0; kk < 2; ++kk) {                          \
        int row = wr * 128 + (MH) * 64 + mm * 16 + (l & 15);                        \
        int cl = kk * 4 + (l >> 4);                                                 \
        dst[mm][kk] = *(const bf16x8*)((const char*)(srcbuf) + row * 128 +          \
                                       ((cl ^ (row & 7)) << 4));                    \
    }

#define LOAD_BV(dst, NH, srcbuf)                                                    \
    _Pragma("unroll") for (int nn = 0; nn < 2; ++nn)                                \
        _Pragma("unroll") for (int kk = 0; kk < 2; ++kk) {                          \
        int row = wc * 64 + (NH) * 32 + nn * 16 + (l & 15);                         \
        int cl = kk * 4 + (l >> 4);                                                 \
        dst[nn][kk] = *(const bf16x8*)((const char*)(srcbuf) + row * 128 +          \
                                       ((cl ^ (row & 7)) << 4));                    \
    }

#define MFMA_Q(MH, NH, AF, BV)                                                      \
    __builtin_amdgcn_s_setprio(1);                                                  \
    _Pragma("unroll") for (int mm = 0; mm < 4; ++mm)                                \
        _Pragma("unroll") for (int nn = 0; nn < 2; ++nn)                            \
            _Pragma("unroll") for (int kk = 0; kk < 2; ++kk)                        \
        acc[(MH) * 4 + mm][(NH) * 2 + nn] = __builtin_amdgcn_mfma_f32_16x16x32_bf16(\
            AF[mm][kk], BV[nn][kk], acc[(MH) * 4 + mm][(NH) * 2 + nn], 0, 0, 0);    \
    __builtin_amdgcn_s_setprio(0);

#define PHASE(READS, STAGES, MFMAS)                                                 \
    {                                                                               \
        READS;                                                                      \
        STAGES;                                                                     \
        asm volatile("s_waitcnt vmcnt(2)");                                         \
        __builtin_amdgcn_s_barrier();                                               \
        MFMAS;                                                                      \
        __builtin_amdgcn_sched_barrier(0);                                          \
    }

#define ITER(t, AF0, BV0, AF0N, BV0N)                                               \
    {                                                                               \
        const int cur = (t) & 1;                                                    \
        const unsigned short* curA = sA[cur];                                       \
        const unsigned short* curB = sB[cur];                                       \
        const unsigned short* oAc = sA[cur ^ 1];                                    \
        const unsigned short* oBc = sB[cur ^ 1];                                    \
        unsigned short* oA = (unsigned short*)sA[cur ^ 1];                          \
        unsigned short* oB = (unsigned short*)sB[cur ^ 1];                          \
        const int k1 = ((t) + 1 < NT ? (t) + 1 : NT - 1) << 6;                      \
        bf16x8 af1[4][2], bv1[2][2];                                                \
        PHASE(LOAD_BV(bv1, 1, curB), STAGE_A0(k1, oA), MFMA_Q(0, 0, AF0, BV0));     \
        PHASE(LOAD_AF(af1, 1, curA), STAGE_B0(k1, oB), MFMA_Q(0, 1, AF0, bv1));     \
        PHASE(LOAD_AF(AF0N, 0, oAc), STAGE_B1(k1, oB), MFMA_Q(1, 1, af1, bv1));     \
        PHASE(LOAD_BV(BV0N, 0, oBc), STAGE_A1(k1, oA), MFMA_Q(1, 0, af1, BV0));     \
    }

__global__ __launch_bounds__(512, 2) void gemm_bt256(
        const unsigned short* __restrict__ A,
        const unsigned short* __restrict__ B,
        float* __restrict__ C, int M, int N, int K) {
    __shared__ unsigned short sA[2][256 * 64];
    __shared__ unsigned short sB[2][256 * 64];
    const int tid = threadIdx.x;
    const int l = tid & 63;
    const int wid = tid >> 6;
    const int wr = wid >> 2;
    const int wc = wid & 3;

    // bijective XCD swizzle (nwg % 8 == 0); by-fastest for B-panel L2 locality
    const int nbx = N >> 8, nby = M >> 8;
    const int cpx = (nbx * nby) >> 3;
    const int swz = ((int)blockIdx.x & 7) * cpx + ((int)blockIdx.x >> 3);
    const int by = swz % nby;
    const int bx = swz / nby;
    const long browBase = (long)by << 8;
    const long bcolBase = (long)bx << 8;

    const int NT = K >> 6;

    f32x4 acc[8][4] = {};
    bf16x8 afA[4][2], bvA[2][2];
    bf16x8 afB[4][2], bvB[2][2];

    // prologue: stage A0,B0,B1(tile0); drain; stage A1(tile0) (stays in
    // flight = steady q1-entry FIFO); barrier; preload af0,bv0 of tile0.
    STAGE_A0(0, sA[0]);
    STAGE_B0(0, sB[0]);
    STAGE_B1(0, sB[0]);
    asm volatile("s_waitcnt vmcnt(0)");
    STAGE_A1(0, sA[0]);
    __builtin_amdgcn_s_barrier();
    LOAD_AF(afA, 0, sA[0]);
    LOAD_BV(bvA, 0, sB[0]);
    __builtin_amdgcn_sched_barrier(0);

    for (int t = 0; t < NT; t += 2) {
        ITER(t, afA, bvA, afB, bvB);
        ITER(t + 1, afB, bvB, afA, bvA);
    }

    // drain in-flight dummy stages / dummy prefetch reads before epilogue
    asm volatile("s_waitcnt vmcnt(0) lgkmcnt(0)");

    // epilogue: C/D layout col = lane&15, row = (lane>>4)*4 + reg
    const int er = (l >> 4) * 4;
    const int ec = l & 15;
#pragma unroll
    for (int mm = 0; mm < 8; ++mm) {
#pragma unroll
        for (int nn = 0; nn < 4; ++nn) {
            long row = browBase + wr * 128 + mm * 16 + er;
            long col = bcolBase + wc * 64 + nn * 16 + ec;
            float* cp = C + row * N + col;
#pragma unroll
            for (int r = 0; r < 4; ++r)
                cp[(long)r * N] = acc[mm][nn][r];
        }
    }
}

// ---------- launch ----------
extern "C" void kernel_launch(void* const* d_in, const int* in_sizes, int n_in,
                              void* d_out, int out_size, void* d_ws, size_t ws_size,
                              hipStream_t stream) {
    const float* x = (const float*)d_in[0];
    const float* W = (const float*)d_in[1];
    float* out = (float*)d_out;

    const int K = 4096;
    const int Nout = in_sizes[1] / K;             // 4096
    const size_t Mrows = (size_t)in_sizes[0] / K; // 8192

    char* ws = (char*)d_ws;
    unsigned short* Xsp = (unsigned short*)ws;
    unsigned short* Wb = (unsigned short*)(ws + Mrows * K * 2);
    unsigned int* ma = (unsigned int*)(ws + Mrows * K * 2 + (size_t)Nout * K * 2);
    unsigned int* mw = ma + K;

    hipMemsetAsync(ma, 0, 2 * K * sizeof(unsigned int), stream);

    dim3 blk(256);
    {
        int xBlocks = (int)(Mrows / 64);              // 128
        int wBlocks = Nout / 64;                      // 64
        dim3 g(K / 1024, xBlocks + wBlocks);
        maxes_kernel<<<g, blk, 0, stream>>>(x, (int)Mrows, W, Nout, ma, mw, Wb, K, xBlocks);
    }
    {
        size_t ngroups = Mrows * K / 4;
        prune_kernel<<<dim3(2048), blk, 0, stream>>>(x, ma, mw, Xsp, ngroups, K);
    }
    {
        dim3 g((unsigned)((Mrows / 256) * (Nout / 256)));
        gemm_bt256<<<g, dim3(512), 0, stream>>>(Xsp, Wb, out, (int)Mrows, Nout, K);
    }
}

// Round 17
// 349.806 us; speedup vs baseline: 1.5835x; 1.5835x over previous
//
#include <hip/hip_runtime.h>
#include <hip/hip_bf16.h>

// ---------- helpers ----------

__device__ __forceinline__ unsigned short f2bf(float f) {
    unsigned u = __float_as_uint(f);
    unsigned r = u + 0x7fffu + ((u >> 16) & 1u);
    return (unsigned short)(r >> 16);
}

typedef __bf16 bf16_t;
typedef bf16_t bf16x8 __attribute__((ext_vector_type(8)));
typedef float f32x4 __attribute__((ext_vector_type(4)));

typedef const __attribute__((address_space(1))) unsigned int* gptr_t;
typedef __attribute__((address_space(3))) unsigned int* lptr_t;

__device__ __forceinline__ void gload_lds16(const void* g, void* l) {
    __builtin_amdgcn_global_load_lds((gptr_t)g, (lptr_t)l, 16, 0, 0);
}

// ---------- kernel 1: fused column-max of |x| AND column-max+convert of W ----------
__global__ void maxes_kernel(const float* __restrict__ x, int xrows,
                             const float* __restrict__ W, int wrows,
                             unsigned int* __restrict__ ma, unsigned int* __restrict__ mw,
                             unsigned short* __restrict__ Wb, int cols, int xBlocks) {
    int c = (blockIdx.x * blockDim.x + threadIdx.x) * 4;
    if (c >= cols) return;
    float m0 = 0.f, m1 = 0.f, m2 = 0.f, m3 = 0.f;
    if ((int)blockIdx.y < xBlocks) {
        int r0 = blockIdx.y * 64;
        int r1 = min(r0 + 64, xrows);
        const float* p = x + (size_t)r0 * cols + c;
        for (int r = r0; r < r1; ++r, p += cols) {
            float4 v = *(const float4*)p;
            m0 = fmaxf(m0, fabsf(v.x));
            m1 = fmaxf(m1, fabsf(v.y));
            m2 = fmaxf(m2, fabsf(v.z));
            m3 = fmaxf(m3, fabsf(v.w));
        }
        atomicMax(ma + c + 0, __float_as_uint(m0));
        atomicMax(ma + c + 1, __float_as_uint(m1));
        atomicMax(ma + c + 2, __float_as_uint(m2));
        atomicMax(ma + c + 3, __float_as_uint(m3));
    } else {
        int r0 = ((int)blockIdx.y - xBlocks) * 64;
        int r1 = min(r0 + 64, wrows);
        const float* p = W + (size_t)r0 * cols + c;
        unsigned short* q = Wb + (size_t)r0 * cols + c;
        for (int r = r0; r < r1; ++r, p += cols, q += cols) {
            float4 v = *(const float4*)p;
            ushort4 o;
            o.x = f2bf(v.x); o.y = f2bf(v.y); o.z = f2bf(v.z); o.w = f2bf(v.w);
            *(ushort4*)q = o;
            m0 = fmaxf(m0, fabsf(v.x));
            m1 = fmaxf(m1, fabsf(v.y));
            m2 = fmaxf(m2, fabsf(v.z));
            m3 = fmaxf(m3, fabsf(v.w));
        }
        atomicMax(mw + c + 0, __float_as_uint(m0));
        atomicMax(mw + c + 1, __float_as_uint(m1));
        atomicMax(mw + c + 2, __float_as_uint(m2));
        atomicMax(mw + c + 3, __float_as_uint(m3));
    }
}

// ---------- kernel 2: 2:4 prune of (x/s), s computed inline ----------
__global__ void prune_kernel(const float* __restrict__ x,
                             const unsigned int* __restrict__ ma,
                             const unsigned int* __restrict__ mw,
                             unsigned short* __restrict__ xsp, size_t ngroups, int cols) {
    size_t g = (size_t)blockIdx.x * blockDim.x + threadIdx.x;
    size_t stride = (size_t)gridDim.x * blockDim.x;
    for (; g < ngroups; g += stride) {
        size_t e = g * 4;
        int cb = (int)(e & (size_t)(cols - 1));
        float4 v = *(const float4*)(x + e);
        uint4 mav = *(const uint4*)(ma + cb);
        uint4 mwv = *(const uint4*)(mw + cb);
        float s0 = sqrtf(__uint_as_float(mav.x) / fmaxf(__uint_as_float(mwv.x), 1e-8f));
        float s1 = sqrtf(__uint_as_float(mav.y) / fmaxf(__uint_as_float(mwv.y), 1e-8f));
        float s2 = sqrtf(__uint_as_float(mav.z) / fmaxf(__uint_as_float(mwv.z), 1e-8f));
        float s3 = sqrtf(__uint_as_float(mav.w) / fmaxf(__uint_as_float(mwv.w), 1e-8f));
        float a0 = fabsf(v.x / s0);
        float a1 = fabsf(v.y / s1);
        float a2 = fabsf(v.z / s2);
        float a3 = fabsf(v.w / s3);
        int r0 = 0, r1 = 0, r2 = 0, r3 = 0;
        if (a1 > a0) r0++; else r1++;
        if (a2 > a0) r0++; else r2++;
        if (a3 > a0) r0++; else r3++;
        if (a2 > a1) r1++; else r2++;
        if (a3 > a1) r1++; else r3++;
        if (a3 > a2) r2++; else r3++;
        ushort4 o;
        o.x = (r0 < 2) ? f2bf(v.x) : (unsigned short)0;
        o.y = (r1 < 2) ? f2bf(v.y) : (unsigned short)0;
        o.z = (r2 < 2) ? f2bf(v.z) : (unsigned short)0;
        o.w = (r3 < 2) ? f2bf(v.w) : (unsigned short)0;
        *(ushort4*)(xsp + e) = o;
    }
}

// ---------- kernel 3: 256x256 bf16 B^T GEMM, 2 phases/K-tile (R14 best) ----------
// ONLY change vs R14: the manual `s_waitcnt lgkmcnt(0)` after each barrier is
// REMOVED. The ds_reads are compiler-visible, so hipcc emits minimal COUNTED
// lgkm waits per MFMA operand group -> MFMA cluster starts when its first
// operands land, overlapping the read tail. Cross-wave ordering (barriers,
// vmcnt gates, region ledger) unchanged from the validated R14 kernel.

template <int ISB, int H>
__device__ __forceinline__ void stage_half(const unsigned short* __restrict__ G, int ldk,
                                           long blockBase, int k0, unsigned short* sbuf,
                                           int wid, int l) {
#pragma unroll
    for (int j = 0; j < 2; ++j) {
        int rho0;
        if (ISB) rho0 = ((wid * 8) & 31) + (wid >> 2) * 64 + H * 32 + j * 128;
        else     rho0 = wid * 8 + H * 64 + j * 128;
        int rho = rho0 + (l >> 3);
        int c = l & 7;
        const unsigned short* src =
            G + (size_t)(blockBase + rho) * ldk + k0 + ((c ^ (rho & 7)) << 3);
        gload_lds16(src, (char*)sbuf + rho0 * 128);
    }
}

#define STAGE_A0(k, buf) stage_half<0, 0>(A, K, browBase, (k), (buf), wid, l)
#define STAGE_A1(k, buf) stage_half<0, 1>(A, K, browBase, (k), (buf), wid, l)
#define STAGE_B0(k, buf) stage_half<1, 0>(B, K, bcolBase, (k), (buf), wid, l)
#define STAGE_B1(k, buf) stage_half<1, 1>(B, K, bcolBase, (k), (buf), wid, l)

#define LOAD_AF(dst, MH, srcbuf)                                                    \
    _Pragma("unroll") for (int mm = 0; mm < 4; ++mm)                                \
        _Pragma("unroll") for (int kk = 0; kk < 2; ++kk) {                          \
        int row = wr * 128 + (MH) * 64 + mm * 16 + (l & 15);                        \
        int cl = kk * 4 + (l >> 4);                                                 \
        dst[mm][kk] = *(const bf16x8*)((const char*)(srcbuf) + row * 128 +          \
                                       ((cl ^ (row & 7)) << 4));                    \
    }

#define LOAD_BV(dst, NH, srcbuf)                                                    \
    _Pragma("unroll") for (int nn = 0; nn < 2; ++nn)                                \
        _Pragma("unroll") for (int kk = 0; kk < 2; ++kk) {                          \
        int row = wc * 64 + (NH) * 32 + nn * 16 + (l & 15);                         \
        int cl = kk * 4 + (l >> 4);                                                 \
        dst[nn][kk] = *(const bf16x8*)((const char*)(srcbuf) + row * 128 +          \
                                       ((cl ^ (row & 7)) << 4));                    \
    }

#define MFMA_NHALF(MH, AFS, BV0, BV1)                                               \
    _Pragma("unroll") for (int mm = 0; mm < 4; ++mm)                                \
        _Pragma("unroll") for (int nn = 0; nn < 2; ++nn)                            \
            _Pragma("unroll") for (int kk = 0; kk < 2; ++kk) {                      \
        acc[(MH) * 4 + mm][nn] = __builtin_amdgcn_mfma_f32_16x16x32_bf16(           \
            AFS[mm][kk], BV0[nn][kk], acc[(MH) * 4 + mm][nn], 0, 0, 0);             \
        acc[(MH) * 4 + mm][2 + nn] = __builtin_amdgcn_mfma_f32_16x16x32_bf16(       \
            AFS[mm][kk], BV1[nn][kk], acc[(MH) * 4 + mm][2 + nn], 0, 0, 0);         \
    }

#define ITER(t, AF0, BV0, BV1, AF0N, BV0N, BV1N)                                    \
    {                                                                               \
        const int cur = (t) & 1;                                                    \
        const unsigned short* curA = sA[cur];                                       \
        const unsigned short* oAc = sA[cur ^ 1];                                    \
        const unsigned short* oBc = sB[cur ^ 1];                                    \
        unsigned short* oA = (unsigned short*)sA[cur ^ 1];                          \
        unsigned short* oB = (unsigned short*)sB[cur ^ 1];                          \
        unsigned short* cA = (unsigned short*)sA[cur];                              \
        unsigned short* cB = (unsigned short*)sB[cur];                              \
        const int k1 = ((t) + 1 < NT ? (t) + 1 : NT - 1) << 6;                      \
        const int k2 = ((t) + 2 < NT ? (t) + 2 : NT - 1) << 6;                      \
        /* ---- p1: quads (0,*) ---- */                                             \
        STAGE_B0(k1, oB);                                                           \
        STAGE_A1(k1, oA);                                                           \
        __builtin_amdgcn_s_barrier();                                               \
        __builtin_amdgcn_s_setprio(1);                                              \
        LOAD_AF(af1, 1, curA);                                                      \
        MFMA_NHALF(0, AF0, BV0, BV1);                                               \
        __builtin_amdgcn_s_setprio(0);                                              \
        __builtin_amdgcn_sched_barrier(0);                                          \
        /* ---- p2: quads (1,*), bv reused from registers ---- */                   \
        STAGE_A0(k2, cA);                                                           \
        STAGE_B1(k2, cB);                                                           \
        asm volatile("s_waitcnt vmcnt(4)");                                         \
        __builtin_amdgcn_s_barrier();                                               \
        __builtin_amdgcn_s_setprio(1);                                              \
        LOAD_AF(AF0N, 0, oAc);                                                      \
        MFMA_NHALF(1, af1, BV0, BV1);                                               \
        __builtin_amdgcn_s_setprio(0);                                              \
        __builtin_amdgcn_sched_barrier(0);                                          \
        /* ---- tail: bv prefetch for t+1 ---- */                                   \
        LOAD_BV(BV0N, 0, oBc);                                                      \
        LOAD_BV(BV1N, 1, oBc);                                                      \
        __builtin_amdgcn_sched_barrier(0);                                          \
    }

__global__ __launch_bounds__(512, 2) void gemm_bt256(
        const unsigned short* __restrict__ A,
        const unsigned short* __restrict__ B,
        float* __restrict__ C, int M, int N, int K) {
    __shared__ unsigned short sA[2][256 * 64];
    __shared__ unsigned short sB[2][256 * 64];
    const int tid = threadIdx.x;
    const int l = tid & 63;
    const int wid = tid >> 6;
    const int wr = wid >> 2;
    const int wc = wid & 3;

    // bijective XCD swizzle (nwg % 8 == 0); by-fastest for B-panel L2 locality
    const int nbx = N >> 8, nby = M >> 8;
    const int cpx = (nbx * nby) >> 3;
    const int swz = ((int)blockIdx.x & 7) * cpx + ((int)blockIdx.x >> 3);
    const int by = swz % nby;
    const int bx = swz / nby;
    const long browBase = (long)by << 8;
    const long bcolBase = (long)bx << 8;

    const int NT = K >> 6;

    f32x4 acc[8][4] = {};
    bf16x8 afA[4][2], bvA0[2][2], bvA1[2][2];
    bf16x8 afB[4][2], bvB0[2][2], bvB1[2][2];
    bf16x8 af1[4][2];

    // prologue: tile0 (8 loads) + A0(1),B1(1) (4 loads); vmcnt(4) drains tile0,
    // leaves A0,B1(1) in flight == steady-state p1-entry FIFO shape.
    STAGE_A0(0, sA[0]);
    STAGE_B0(0, sB[0]);
    STAGE_B1(0, sB[0]);
    STAGE_A1(0, sA[0]);
    STAGE_A0(64, sA[1]);
    STAGE_B1(64, sB[1]);
    asm volatile("s_waitcnt vmcnt(4)");
    __builtin_amdgcn_s_barrier();
    __builtin_amdgcn_sched_barrier(0);

    // preloop: tile0's p1 operand set
    LOAD_AF(afA, 0, sA[0]);
    LOAD_BV(bvA0, 0, sB[0]);
    LOAD_BV(bvA1, 1, sB[0]);
    __builtin_amdgcn_sched_barrier(0);

    for (int t = 0; t < NT; t += 2) {
        ITER(t, afA, bvA0, bvA1, afB, bvB0, bvB1);
        ITER(t + 1, afB, bvB0, bvB1, afA, bvA0, bvA1);
    }

    // drain in-flight dummy stages / dummy prefetch reads before epilogue
    asm volatile("s_waitcnt vmcnt(0) lgkmcnt(0)");

    // epilogue: C/D layout col = lane&15, row = (lane>>4)*4 + reg
    const int er = (l >> 4) * 4;
    const int ec = l & 15;
#pragma unroll
    for (int mm = 0; mm < 8; ++mm) {
#pragma unroll
        for (int nn = 0; nn < 4; ++nn) {
            long row = browBase + wr * 128 + mm * 16 + er;
            long col = bcolBase + wc * 64 + nn * 16 + ec;
            float* cp = C + row * N + col;
#pragma unroll
            for (int r = 0; r < 4; ++r)
                cp[(long)r * N] = acc[mm][nn][r];
        }
    }
}

// ---------- launch ----------
extern "C" void kernel_launch(void* const* d_in, const int* in_sizes, int n_in,
                              void* d_out, int out_size, void* d_ws, size_t ws_size,
                              hipStream_t stream) {
    const float* x = (const float*)d_in[0];
    const float* W = (const float*)d_in[1];
    float* out = (float*)d_out;

    const int K = 4096;
    const int Nout = in_sizes[1] / K;             // 4096
    const size_t Mrows = (size_t)in_sizes[0] / K; // 8192

    char* ws = (char*)d_ws;
    unsigned short* Xsp = (unsigned short*)ws;
    unsigned short* Wb = (unsigned short*)(ws + Mrows * K * 2);
    unsigned int* ma = (unsigned int*)(ws + Mrows * K * 2 + (size_t)Nout * K * 2);
    unsigned int* mw = ma + K;

    hipMemsetAsync(ma, 0, 2 * K * sizeof(unsigned int), stream);

    dim3 blk(256);
    {
        int xBlocks = (int)(Mrows / 64);              // 128
        int wBlocks = Nout / 64;                      // 64
        dim3 g(K / 1024, xBlocks + wBlocks);
        maxes_kernel<<<g, blk, 0, stream>>>(x, (int)Mrows, W, Nout, ma, mw, Wb, K, xBlocks);
    }
    {
        size_t ngroups = Mrows * K / 4;
        prune_kernel<<<dim3(2048), blk, 0, stream>>>(x, ma, mw, Xsp, ngroups, K);
    }
    {
        dim3 g((unsigned)((Mrows / 256) * (Nout / 256)));
        gemm_bt256<<<g, dim3(512), 0, stream>>>(Xsp, Wb, out, (int)Mrows, Nout, K);
    }
}